// Round 3
// baseline (1017.722 us; speedup 1.0000x reference)
//
#include <hip/hip_runtime.h>
#include <hip/hip_bf16.h>

// sparselinear: out[b*S + s] = sum_{e: row[e]==s} x[b*G + col[e]] * W[e] + bias[s]
// B=64 (== wavefront), G=20000, S=200000, NNZ=2e6.
//
// Pipeline (graph-capture safe, all on `stream`):
//   1. memset bucket counts = 0
//   2. transpose x [B,G] -> xT [G,B]      (lane=batch coalesced gathers)
//   3. bucket histogram (256 rows/bucket), LDS-aggregated
//   4. single-block exclusive scan of 782 bucket counts -> boff, gcur
//   5. bin pass: block-aggregated reservation, scatter packed
//      (localrow,col,w) records into bucket regions (runs ~84B -> L2 combines)
//   6. compute: one block per bucket; LDS tile[256 rows][64 batches]
//      (XOR swizzle), edges streamed coalesced, ds_add_f32 accumulate,
//      bias-initialized, coalesced 64KB epilogue store.

#define WAVE 64
#define RPB 256                 // rows per bucket
#define BIN_EDGES 8192          // edges per binning block (32/thread)
#define MAXBUCK 1024

__device__ __forceinline__ int swz(int r, int b) {
    return (r << 6) + (b ^ (r & 63));   // tile[256][64], XOR-swizzled
}

__global__ void transpose64_kernel(const float* __restrict__ x,
                                   float* __restrict__ xT, int G) {
    __shared__ float tile[64][65];
    const int t  = threadIdx.x;
    const int g0 = blockIdx.x * 64;
    {
        const int j  = t & 63;
        const int b0 = t >> 6;
        if (g0 + j < G) {
            #pragma unroll
            for (int it = 0; it < 16; ++it) {
                const int b = b0 + it * 4;
                tile[j][b] = x[(size_t)b * G + g0 + j];
            }
        }
    }
    __syncthreads();
    {
        const int b  = t & 63;
        const int j0 = t >> 6;
        #pragma unroll
        for (int it = 0; it < 16; ++it) {
            const int j = j0 + it * 4;
            if (g0 + j < G) xT[(size_t)(g0 + j) * WAVE + b] = tile[j][b];
        }
    }
}

__global__ __launch_bounds__(256) void bhist_kernel(
        const int* __restrict__ row, int* __restrict__ gcnt,
        int nnz, int nbuckets) {
    __shared__ int hist[MAXBUCK];
    const int t  = threadIdx.x;
    const int e0 = blockIdx.x * BIN_EDGES;
    for (int j = t; j < nbuckets; j += 256) hist[j] = 0;
    __syncthreads();
    #pragma unroll 4
    for (int k = 0; k < BIN_EDGES / 256; ++k) {
        const int i = e0 + k * 256 + t;
        if (i < nnz) atomicAdd(&hist[row[i] >> 8], 1);
    }
    __syncthreads();
    for (int j = t; j < nbuckets; j += 256) {
        const int h = hist[j];
        if (h) atomicAdd(&gcnt[j], h);
    }
}

// Single-block exclusive scan of nbuckets (<=4096) counts -> boff[0..nb], gcur.
__global__ __launch_bounds__(256) void bscan_kernel(
        const int* __restrict__ gcnt, int* __restrict__ boff,
        int* __restrict__ gcur, int nbuckets) {
    __shared__ int sd[256];
    const int t = threadIdx.x;
    int v[16];
    int tsum = 0;
    const int base = t * 16;
    #pragma unroll
    for (int k = 0; k < 16; ++k) {
        const int idx = base + k;
        const int c = (idx < nbuckets) ? gcnt[idx] : 0;
        v[k] = tsum;
        tsum += c;
    }
    sd[t] = tsum;
    __syncthreads();
    for (int o = 1; o < 256; o <<= 1) {
        const int a = (t >= o) ? sd[t - o] : 0;
        __syncthreads();
        sd[t] += a;
        __syncthreads();
    }
    const int tex = sd[t] - tsum;
    #pragma unroll
    for (int k = 0; k < 16; ++k) {
        const int idx = base + k;
        if (idx < nbuckets) {
            const int o2 = tex + v[k];
            boff[idx] = o2;
            gcur[idx] = o2;
        }
    }
    if (t == 255) boff[nbuckets] = sd[255];
}

// Block-aggregated bin: LDS hist -> one global atomic per (block,bucket)
// reservation -> scatter into contiguous per-block runs (L2-combinable).
// Record: (localrow<<15 | col, w) -- col<32768, localrow<256.
__global__ __launch_bounds__(256) void bin_kernel(
        const int* __restrict__ row, const int* __restrict__ col,
        const float* __restrict__ w, int* __restrict__ gcur,
        uint2* __restrict__ sedge, int nnz, int nbuckets) {
    __shared__ int hist[MAXBUCK];
    __shared__ int lbase[MAXBUCK];
    const int t  = threadIdx.x;
    const int e0 = blockIdx.x * BIN_EDGES;
    for (int j = t; j < nbuckets; j += 256) hist[j] = 0;
    __syncthreads();
    #pragma unroll 4
    for (int k = 0; k < BIN_EDGES / 256; ++k) {
        const int i = e0 + k * 256 + t;
        if (i < nnz) atomicAdd(&hist[row[i] >> 8], 1);
    }
    __syncthreads();
    for (int j = t; j < nbuckets; j += 256) {
        const int h = hist[j];
        lbase[j] = h ? atomicAdd(&gcur[j], h) : 0;
        hist[j] = 0;   // reuse as local cursor
    }
    __syncthreads();
    #pragma unroll 4
    for (int k = 0; k < BIN_EDGES / 256; ++k) {
        const int i = e0 + k * 256 + t;
        if (i < nnz) {
            const int r = row[i];
            const int bk = r >> 8;
            const int pos = lbase[bk] + atomicAdd(&hist[bk], 1);
            sedge[pos] = make_uint2(((unsigned)(r & 255) << 15) | (unsigned)col[i],
                                    __float_as_uint(w[i]));
        }
    }
}

// One block per bucket (256 rows x 64 batches). lane = batch.
// LDS accumulator tile[256][64] (XOR swizzle: 2-way bank aliasing = free),
// initialized with bias. Waves stream 64-record chunks: coalesced stage,
// readlane broadcast, 4x-unrolled xT gathers, ds_add_f32 accumulate.
// Epilogue: coalesced dword stores (conflict-free swizzled LDS reads).
__global__ __launch_bounds__(256) void compute_kernel(
        const float* __restrict__ xT,
        const uint2* __restrict__ sedge,
        const int* __restrict__ boff,
        const float* __restrict__ bias,
        float* __restrict__ out, int S) {
    __shared__ float tile[RPB * 64];   // 64 KB
    const int lane = threadIdx.x & 63;
    const int wv   = threadIdx.x >> 6;
    const int r0   = blockIdx.x * RPB;
    const int nrows = min(RPB, S - r0);

    // init: tile[r][b] = bias[r0+r] for all b
    for (int r = wv; r < nrows; r += 4) {
        const float bs = bias[r0 + r];
        tile[swz(r, lane)] = bs;
    }
    __syncthreads();

    const int start = __builtin_amdgcn_readfirstlane(boff[blockIdx.x]);
    const int end   = __builtin_amdgcn_readfirstlane(boff[blockIdx.x + 1]);
    const int n     = end - start;

    for (int base = wv * WAVE; base < n; base += 4 * WAVE) {
        int m = n - base;
        if (m > WAVE) m = WAVE;
        uint2 e = make_uint2(0u, 0u);
        if (lane < m) e = sedge[start + base + lane];
        const int key = (int)e.x;
        const int wbt = (int)e.y;
        int i = 0;
        for (; i + 4 <= m; i += 4) {
            const int k0 = __builtin_amdgcn_readlane(key, i);
            const int k1 = __builtin_amdgcn_readlane(key, i + 1);
            const int k2 = __builtin_amdgcn_readlane(key, i + 2);
            const int k3 = __builtin_amdgcn_readlane(key, i + 3);
            const float w0 = __int_as_float(__builtin_amdgcn_readlane(wbt, i));
            const float w1 = __int_as_float(__builtin_amdgcn_readlane(wbt, i + 1));
            const float w2 = __int_as_float(__builtin_amdgcn_readlane(wbt, i + 2));
            const float w3 = __int_as_float(__builtin_amdgcn_readlane(wbt, i + 3));
            const float v0 = xT[(k0 & 0x7fff) * WAVE + lane];
            const float v1 = xT[(k1 & 0x7fff) * WAVE + lane];
            const float v2 = xT[(k2 & 0x7fff) * WAVE + lane];
            const float v3 = xT[(k3 & 0x7fff) * WAVE + lane];
            atomicAdd(&tile[swz(k0 >> 15, lane)], v0 * w0);
            atomicAdd(&tile[swz(k1 >> 15, lane)], v1 * w1);
            atomicAdd(&tile[swz(k2 >> 15, lane)], v2 * w2);
            atomicAdd(&tile[swz(k3 >> 15, lane)], v3 * w3);
        }
        for (; i < m; ++i) {
            const int   k0 = __builtin_amdgcn_readlane(key, i);
            const float w0 = __int_as_float(__builtin_amdgcn_readlane(wbt, i));
            const float v0 = xT[(k0 & 0x7fff) * WAVE + lane];
            atomicAdd(&tile[swz(k0 >> 15, lane)], v0 * w0);
        }
    }
    __syncthreads();

    // store: wave wv -> batches [wv*16, wv*16+16); lane = row offset (x4 chunks)
    #pragma unroll
    for (int k = 0; k < 16; ++k) {
        const int b = wv * 16 + k;
        #pragma unroll
        for (int rc = 0; rc < RPB; rc += 64) {
            const int r = rc + lane;
            if (r0 + r < S)
                out[(size_t)b * S + r0 + r] = tile[swz(r, b)];
        }
    }
}

extern "C" void kernel_launch(void* const* d_in, const int* in_sizes, int n_in,
                              void* d_out, int out_size, void* d_ws, size_t ws_size,
                              hipStream_t stream) {
    const float* x    = (const float*)d_in[0];
    const float* W    = (const float*)d_in[1];
    const float* bias = (const float*)d_in[2];
    const int*   idx  = (const int*)d_in[3];

    const int NNZ = in_sizes[1];
    const int S   = in_sizes[2];
    const int B   = out_size / S;        // 64
    const int G   = in_sizes[0] / B;     // 20000
    const int* rowi = idx;
    const int* coli = idx + NNZ;
    float* out = (float*)d_out;

    const int nbuckets = (S + RPB - 1) / RPB;   // 782

    // workspace layout (256B-aligned slabs)
    char* ws = (char*)d_ws;
    size_t o = 0;
    auto alloc = [&](size_t bytes) {
        void* p = ws + o;
        o = (o + bytes + 255) & ~(size_t)255;
        return p;
    };
    float* xT    = (float*)alloc((size_t)G * B * sizeof(float));
    int*   gcnt  = (int*)  alloc(MAXBUCK * sizeof(int));
    int*   boff  = (int*)  alloc((MAXBUCK + 1) * sizeof(int));
    int*   gcur  = (int*)  alloc(MAXBUCK * sizeof(int));
    uint2* sedge = (uint2*)alloc((size_t)NNZ * sizeof(uint2));
    (void)ws_size; (void)n_in;

    hipMemsetAsync(gcnt, 0, nbuckets * sizeof(int), stream);

    const int tgrid = (G + 63) / 64;
    transpose64_kernel<<<tgrid, 256, 0, stream>>>(x, xT, G);

    const int bgrid = (NNZ + BIN_EDGES - 1) / BIN_EDGES;   // 245
    bhist_kernel<<<bgrid, 256, 0, stream>>>(rowi, gcnt, NNZ, nbuckets);
    bscan_kernel<<<1, 256, 0, stream>>>(gcnt, boff, gcur, nbuckets);
    bin_kernel<<<bgrid, 256, 0, stream>>>(rowi, coli, W, gcur, sedge,
                                          NNZ, nbuckets);

    compute_kernel<<<nbuckets, 256, 0, stream>>>(xT, sedge, boff, bias, out, S);
}

// Round 4
// 412.187 us; speedup vs baseline: 2.4691x; 2.4691x over previous
//
#include <hip/hip_runtime.h>
#include <hip/hip_bf16.h>

// sparselinear: out[b*S + s] = sum_{e: row[e]==s} x[b*G + col[e]] * W[e] + bias[s]
// B=64 (== wavefront), G=20000, S=200000, NNZ=2e6.
//
// Pipeline (graph-capture safe, all on `stream`):
//   1. memset bucket counts = 0
//   2. transpose x [B,G] -> xT [G,B]      (lane=batch coalesced gathers)
//   3. bucket histogram (64 rows/bucket -> 3125 buckets), LDS-aggregated
//   4. single-block exclusive scan of bucket counts -> boff, gcur
//   5. bin pass: block-aggregated reservation, scatter packed
//      (localrow<<15|col, w) records into bucket regions
//   6. compute: one block per bucket, wave w owns rows [16w,16w+16) in
//      16 REGISTER accumulators (no LDS tile in hot loop, no atomics).
//      Row index is wave-uniform (readlane) -> uniform 16-way switch.
//      Epilogue through a 16KB LDS tile for coalesced output stores.

#define WAVE 64
#define RPB 64                  // rows per bucket
#define BIN_EDGES 8192          // edges per binning block (32/thread)
#define MAXBUCK 4096

__device__ __forceinline__ int swz(int r, int b) {
    return (r << 6) + (b ^ (r & 63));   // tile[64][64], XOR-swizzled (2-way free)
}

__global__ void transpose64_kernel(const float* __restrict__ x,
                                   float* __restrict__ xT, int G) {
    __shared__ float tile[64][65];
    const int t  = threadIdx.x;
    const int g0 = blockIdx.x * 64;
    {
        const int j  = t & 63;
        const int b0 = t >> 6;
        if (g0 + j < G) {
            #pragma unroll
            for (int it = 0; it < 16; ++it) {
                const int b = b0 + it * 4;
                tile[j][b] = x[(size_t)b * G + g0 + j];
            }
        }
    }
    __syncthreads();
    {
        const int b  = t & 63;
        const int j0 = t >> 6;
        #pragma unroll
        for (int it = 0; it < 16; ++it) {
            const int j = j0 + it * 4;
            if (g0 + j < G) xT[(size_t)(g0 + j) * WAVE + b] = tile[j][b];
        }
    }
}

__global__ __launch_bounds__(256) void bhist_kernel(
        const int* __restrict__ row, int* __restrict__ gcnt,
        int nnz, int nbuckets) {
    __shared__ int hist[MAXBUCK];
    const int t  = threadIdx.x;
    const int e0 = blockIdx.x * BIN_EDGES;
    for (int j = t; j < nbuckets; j += 256) hist[j] = 0;
    __syncthreads();
    #pragma unroll 4
    for (int k = 0; k < BIN_EDGES / 256; ++k) {
        const int i = e0 + k * 256 + t;
        if (i < nnz) atomicAdd(&hist[row[i] >> 6], 1);
    }
    __syncthreads();
    for (int j = t; j < nbuckets; j += 256) {
        const int h = hist[j];
        if (h) atomicAdd(&gcnt[j], h);
    }
}

// Single-block exclusive scan of nbuckets (<=4096) counts -> boff[0..nb], gcur.
__global__ __launch_bounds__(256) void bscan_kernel(
        const int* __restrict__ gcnt, int* __restrict__ boff,
        int* __restrict__ gcur, int nbuckets) {
    __shared__ int sd[256];
    const int t = threadIdx.x;
    int v[16];
    int tsum = 0;
    const int base = t * 16;
    #pragma unroll
    for (int k = 0; k < 16; ++k) {
        const int idx = base + k;
        const int c = (idx < nbuckets) ? gcnt[idx] : 0;
        v[k] = tsum;
        tsum += c;
    }
    sd[t] = tsum;
    __syncthreads();
    for (int o = 1; o < 256; o <<= 1) {
        const int a = (t >= o) ? sd[t - o] : 0;
        __syncthreads();
        sd[t] += a;
        __syncthreads();
    }
    const int tex = sd[t] - tsum;
    #pragma unroll
    for (int k = 0; k < 16; ++k) {
        const int idx = base + k;
        if (idx < nbuckets) {
            const int o2 = tex + v[k];
            boff[idx] = o2;
            gcur[idx] = o2;
        }
    }
    if (t == 255) boff[nbuckets] = sd[255];
}

// Block-aggregated bin: LDS hist -> one global atomic per (block,bucket)
// reservation -> scatter into contiguous per-block runs.
// Record: (localrow<<15 | col, w) -- col<32768, localrow<64.
__global__ __launch_bounds__(256) void bin_kernel(
        const int* __restrict__ row, const int* __restrict__ col,
        const float* __restrict__ w, int* __restrict__ gcur,
        uint2* __restrict__ sedge, int nnz, int nbuckets) {
    __shared__ int hist[MAXBUCK];
    __shared__ int lbase[MAXBUCK];
    const int t  = threadIdx.x;
    const int e0 = blockIdx.x * BIN_EDGES;
    for (int j = t; j < nbuckets; j += 256) hist[j] = 0;
    __syncthreads();
    #pragma unroll 4
    for (int k = 0; k < BIN_EDGES / 256; ++k) {
        const int i = e0 + k * 256 + t;
        if (i < nnz) atomicAdd(&hist[row[i] >> 6], 1);
    }
    __syncthreads();
    for (int j = t; j < nbuckets; j += 256) {
        const int h = hist[j];
        lbase[j] = h ? atomicAdd(&gcur[j], h) : 0;
        hist[j] = 0;   // reuse as local cursor
    }
    __syncthreads();
    #pragma unroll 4
    for (int k = 0; k < BIN_EDGES / 256; ++k) {
        const int i = e0 + k * 256 + t;
        if (i < nnz) {
            const int r = row[i];
            const int bk = r >> 6;
            const int pos = lbase[bk] + atomicAdd(&hist[bk], 1);
            sedge[pos] = make_uint2(((unsigned)(r & 63) << 15) | (unsigned)col[i],
                                    __float_as_uint(w[i]));
        }
    }
}

// One block per 64-row bucket. lane = batch. Wave w owns local rows
// [16w, 16w+16) in 16 register accumulators; each wave scans all bucket
// edges (readlane broadcast -> row is wave-uniform -> uniform branch +
// uniform 16-way switch, no divergence, no atomics, no LDS in hot loop).
__global__ __launch_bounds__(256, 8) void compute_kernel(
        const float* __restrict__ xT,
        const uint2* __restrict__ sedge,
        const int* __restrict__ boff,
        const float* __restrict__ bias,
        float* __restrict__ out, int S) {
    __shared__ float tile[RPB * 64];   // 16 KB, epilogue only
    const int lane = threadIdx.x & 63;
    const int wv   = threadIdx.x >> 6;
    const int r0   = blockIdx.x * RPB;

    const int start = __builtin_amdgcn_readfirstlane(boff[blockIdx.x]);
    const int end   = __builtin_amdgcn_readfirstlane(boff[blockIdx.x + 1]);
    const int n     = end - start;

    float acc[16];
    #pragma unroll
    for (int j = 0; j < 16; ++j) acc[j] = 0.f;

    for (int base = 0; base < n; base += WAVE) {
        int m = n - base;
        if (m > WAVE) m = WAVE;
        uint2 e = make_uint2(0u, 0u);
        if (lane < m) e = sedge[start + base + lane];
        const int ekey = (int)e.x;
        const int ewgt = (int)e.y;
        for (int i = 0; i < m; ++i) {
            const int key = __builtin_amdgcn_readlane(ekey, i);
            const int r   = key >> 15;            // local row, uniform
            if ((r >> 4) == wv) {
                const float wgt = __int_as_float(
                    __builtin_amdgcn_readlane(ewgt, i));
                const float v = xT[(key & 0x7fff) * WAVE + lane];
                switch (r & 15) {
                    case 0:  acc[0]  += v * wgt; break;
                    case 1:  acc[1]  += v * wgt; break;
                    case 2:  acc[2]  += v * wgt; break;
                    case 3:  acc[3]  += v * wgt; break;
                    case 4:  acc[4]  += v * wgt; break;
                    case 5:  acc[5]  += v * wgt; break;
                    case 6:  acc[6]  += v * wgt; break;
                    case 7:  acc[7]  += v * wgt; break;
                    case 8:  acc[8]  += v * wgt; break;
                    case 9:  acc[9]  += v * wgt; break;
                    case 10: acc[10] += v * wgt; break;
                    case 11: acc[11] += v * wgt; break;
                    case 12: acc[12] += v * wgt; break;
                    case 13: acc[13] += v * wgt; break;
                    case 14: acc[14] += v * wgt; break;
                    case 15: acc[15] += v * wgt; break;
                }
            }
        }
    }

    // epilogue: acc -> LDS tile (add bias), then coalesced stores
    #pragma unroll
    for (int j = 0; j < 16; ++j) {
        const int rl  = wv * 16 + j;
        const int row = r0 + rl;
        const float bs = (row < S) ? bias[row] : 0.f;
        tile[swz(rl, lane)] = acc[j] + bs;
    }
    __syncthreads();
    #pragma unroll
    for (int k = 0; k < 16; ++k) {
        const int b = wv * 16 + k;
        if (r0 + lane < S)
            out[(size_t)b * S + r0 + lane] = tile[swz(lane, b)];
    }
}

extern "C" void kernel_launch(void* const* d_in, const int* in_sizes, int n_in,
                              void* d_out, int out_size, void* d_ws, size_t ws_size,
                              hipStream_t stream) {
    const float* x    = (const float*)d_in[0];
    const float* W    = (const float*)d_in[1];
    const float* bias = (const float*)d_in[2];
    const int*   idx  = (const int*)d_in[3];

    const int NNZ = in_sizes[1];
    const int S   = in_sizes[2];
    const int B   = out_size / S;        // 64
    const int G   = in_sizes[0] / B;     // 20000
    const int* rowi = idx;
    const int* coli = idx + NNZ;
    float* out = (float*)d_out;

    const int nbuckets = (S + RPB - 1) / RPB;   // 3125

    // workspace layout (256B-aligned slabs)
    char* ws = (char*)d_ws;
    size_t o = 0;
    auto alloc = [&](size_t bytes) {
        void* p = ws + o;
        o = (o + bytes + 255) & ~(size_t)255;
        return p;
    };
    float* xT    = (float*)alloc((size_t)G * B * sizeof(float));
    int*   gcnt  = (int*)  alloc(MAXBUCK * sizeof(int));
    int*   boff  = (int*)  alloc((MAXBUCK + 1) * sizeof(int));
    int*   gcur  = (int*)  alloc(MAXBUCK * sizeof(int));
    uint2* sedge = (uint2*)alloc((size_t)NNZ * sizeof(uint2));
    (void)ws_size; (void)n_in;

    hipMemsetAsync(gcnt, 0, nbuckets * sizeof(int), stream);

    const int tgrid = (G + 63) / 64;
    transpose64_kernel<<<tgrid, 256, 0, stream>>>(x, xT, G);

    const int bgrid = (NNZ + BIN_EDGES - 1) / BIN_EDGES;   // 245
    bhist_kernel<<<bgrid, 256, 0, stream>>>(rowi, gcnt, NNZ, nbuckets);
    bscan_kernel<<<1, 256, 0, stream>>>(gcnt, boff, gcur, nbuckets);
    bin_kernel<<<bgrid, 256, 0, stream>>>(rowi, coli, W, gcur, sedge,
                                          NNZ, nbuckets);

    compute_kernel<<<nbuckets, 256, 0, stream>>>(xT, sedge, boff, bias, out, S);
}